// Round 7
// baseline (130.546 us; speedup 1.0000x reference)
//
#include <hip/hip_runtime.h>
#include <hip/hip_bf16.h>
#include <math.h>

// Problem constants
static constexpr int kB = 8;
static constexpr int kH = 8;
static constexpr int kL = 512;
static constexpr int kD = 512;
static constexpr int kDH = 64;     // D/H
static constexpr int kBH = 64;     // B*H
static constexpr int kROWS = kBH * kL;  // 32768

typedef short bf16x8 __attribute__((ext_vector_type(8)));
typedef float f32x4 __attribute__((ext_vector_type(4)));

// RNE float->bf16 (finite inputs only)
__device__ __forceinline__ ushort f2bf(float f) {
    unsigned u = __float_as_uint(f);
    unsigned r = u + 0x7fffu + ((u >> 16) & 1u);
    return (ushort)(r >> 16);
}
__device__ __forceinline__ float bf2f(ushort h) {
    return __uint_as_float((unsigned)h << 16);
}

// gelu with A&S 7.1.26 erf (max abs err ~1.5e-7, monotone-preserving;
// selection/threshold decisions are order-based -> exactly invariant)
__device__ __forceinline__ float gelu_fast(float v) {
    float z = v * 0.70710678118654752440f;
    float az = fabsf(z);
    float t = 1.0f / (1.0f + 0.3275911f * az);
    float ex = __expf(-az * az);
    float poly = t * (0.254829592f + t * (-0.284496736f + t * (1.421413741f +
                 t * (-1.453152027f + t * 1.061405429f))));
    float erfv = 1.0f - poly * ex;
    erfv = (z < 0.0f) ? -erfv : erfv;
    return 0.5f * v * (1.0f + erfv);
}

// ---------------------------------------------------------------------------
// K1: q = xh@W1^T + b1, k = xh@W2^T + b2 as tiled GEMM (fp32 FMA).
// Epilogue writes hi/lo bf16 pairs directly (conversion done once here,
// instead of 8x redundantly in k_adj staging).
// ---------------------------------------------------------------------------
__global__ __launch_bounds__(256) void k_qk(const float* __restrict__ x,
        const float* __restrict__ W1, const float* __restrict__ b1,
        const float* __restrict__ W2, const float* __restrict__ b2,
        ushort* __restrict__ qh, ushort* __restrict__ ql,
        ushort* __restrict__ kh, ushort* __restrict__ kl) {
    int blk = blockIdx.x;              // b*64 + h*8 + lt
    int b = blk >> 6, h = (blk >> 3) & 7, lt = blk & 7;
    __shared__ float xt[64][68];       // [l][c]
    __shared__ float w1t[64][68];      // [d][c]
    __shared__ float w2t[64][68];
    int tid = threadIdx.x;
    #pragma unroll
    for (int r = 0; r < 16; ++r) {
        int e = tid + r * 256;
        int rr = e >> 6, cc = e & 63;
        xt[rr][cc]  = x[(b * kL + lt * 64 + rr) * kD + h * kDH + cc];
        w1t[rr][cc] = W1[rr * 64 + cc];
        w2t[rr][cc] = W2[rr * 64 + cc];
    }
    __syncthreads();
    int ty = tid >> 4, tx = tid & 15;
    float aq[4][4] = {}, ak[4][4] = {};
    #pragma unroll 2
    for (int c = 0; c < 64; c += 4) {
        float4 av[4], wq[4], wk[4];
        #pragma unroll
        for (int a = 0; a < 4; ++a) av[a] = *(const float4*)&xt[ty * 4 + a][c];
        #pragma unroll
        for (int j = 0; j < 4; ++j) {
            wq[j] = *(const float4*)&w1t[tx + 16 * j][c];
            wk[j] = *(const float4*)&w2t[tx + 16 * j][c];
        }
        #pragma unroll
        for (int a = 0; a < 4; ++a)
            #pragma unroll
            for (int j = 0; j < 4; ++j) {
                aq[a][j] = fmaf(av[a].x, wq[j].x, aq[a][j]);
                aq[a][j] = fmaf(av[a].y, wq[j].y, aq[a][j]);
                aq[a][j] = fmaf(av[a].z, wq[j].z, aq[a][j]);
                aq[a][j] = fmaf(av[a].w, wq[j].w, aq[a][j]);
                ak[a][j] = fmaf(av[a].x, wk[j].x, ak[a][j]);
                ak[a][j] = fmaf(av[a].y, wk[j].y, ak[a][j]);
                ak[a][j] = fmaf(av[a].z, wk[j].z, ak[a][j]);
                ak[a][j] = fmaf(av[a].w, wk[j].w, ak[a][j]);
            }
    }
    #pragma unroll
    for (int a = 0; a < 4; ++a)
        #pragma unroll
        for (int j = 0; j < 4; ++j) {
            int row = lt * 64 + ty * 4 + a;
            int col = tx + 16 * j;
            int o = ((b * kH + h) * kL + row) * kDH + col;
            float qv = aq[a][j] + b1[col];
            float kv = ak[a][j] + b2[col];
            ushort qhh = f2bf(qv), khh = f2bf(kv);
            qh[o] = qhh; ql[o] = f2bf(qv - bf2f(qhh));
            kh[o] = khh; kl[o] = f2bf(kv - bf2f(khh));
        }
}

// ---------------------------------------------------------------------------
// K2 (MFMA, split-bf16): adj = gelu(q @ k^T) per (b,h). 64x64 tile, K=64.
// hi/lo staged by pure int4 copy; S = hi*hi + hi*lo + lo*hi (err ~1e-5).
// grid = B*H*8*8 = 4096, 256 thr (4 waves, 2x2 of 32x32).
// ---------------------------------------------------------------------------
__global__ __launch_bounds__(256) void k_adj(const ushort* __restrict__ qh,
        const ushort* __restrict__ ql, const ushort* __restrict__ kh,
        const ushort* __restrict__ kl, float* __restrict__ adj) {
    int blk = blockIdx.x;
    int bh = blk >> 6;
    int it = (blk >> 3) & 7, jt = blk & 7;
    __shared__ ushort ah[64][72], al[64][72];
    __shared__ ushort bh_[64][72], bl[64][72];
    int tid = threadIdx.x;
    int r = tid >> 2, s = tid & 3;
    size_t aoff = (size_t)(bh * kL + it * 64 + r) * kDH + s * 16;
    size_t boff = (size_t)(bh * kL + jt * 64 + r) * kDH + s * 16;
    *(int4*)&ah[r][s * 16]  = *(const int4*)&qh[aoff];
    *(int4*)&ah[r][s * 16 + 8]  = *(const int4*)&qh[aoff + 8];
    *(int4*)&al[r][s * 16]  = *(const int4*)&ql[aoff];
    *(int4*)&al[r][s * 16 + 8]  = *(const int4*)&ql[aoff + 8];
    *(int4*)&bh_[r][s * 16] = *(const int4*)&kh[boff];
    *(int4*)&bh_[r][s * 16 + 8] = *(const int4*)&kh[boff + 8];
    *(int4*)&bl[r][s * 16]  = *(const int4*)&kl[boff];
    *(int4*)&bl[r][s * 16 + 8]  = *(const int4*)&kl[boff + 8];
    __syncthreads();
    int lane = tid & 63, wave = tid >> 6;
    int wm = wave >> 1, wn = wave & 1;
    int am = wm * 32 + (lane & 15);
    int bn = wn * 32 + (lane & 15);
    int coff = (lane >> 4) * 8;
    f32x4 acc[2][2] = {};
    #pragma unroll
    for (int kk = 0; kk < 2; ++kk) {
        bf16x8 afh[2], afl[2], bfh[2], bfl[2];
        #pragma unroll
        for (int fm = 0; fm < 2; ++fm) {
            afh[fm] = *(const bf16x8*)&ah[am + fm * 16][kk * 32 + coff];
            afl[fm] = *(const bf16x8*)&al[am + fm * 16][kk * 32 + coff];
        }
        #pragma unroll
        for (int fn = 0; fn < 2; ++fn) {
            bfh[fn] = *(const bf16x8*)&bh_[bn + fn * 16][kk * 32 + coff];
            bfl[fn] = *(const bf16x8*)&bl[bn + fn * 16][kk * 32 + coff];
        }
        #pragma unroll
        for (int fm = 0; fm < 2; ++fm)
            #pragma unroll
            for (int fn = 0; fn < 2; ++fn) {
                acc[fm][fn] = __builtin_amdgcn_mfma_f32_16x16x32_bf16(
                    afh[fm], bfh[fn], acc[fm][fn], 0, 0, 0);
                acc[fm][fn] = __builtin_amdgcn_mfma_f32_16x16x32_bf16(
                    afh[fm], bfl[fn], acc[fm][fn], 0, 0, 0);
                acc[fm][fn] = __builtin_amdgcn_mfma_f32_16x16x32_bf16(
                    afl[fm], bfh[fn], acc[fm][fn], 0, 0, 0);
            }
    }
    int mrow = it * 64 + wm * 32 + (lane >> 4) * 4;
    int ncol = jt * 64 + wn * 32 + (lane & 15);
    #pragma unroll
    for (int fm = 0; fm < 2; ++fm)
        #pragma unroll
        for (int fn = 0; fn < 2; ++fn)
            #pragma unroll
            for (int rr = 0; rr < 4; ++rr)
                adj[((size_t)bh * kL + mrow + fm * 16 + rr) * kL + ncol + fn * 16] =
                    gelu_fast(acc[fm][fn][rr]);
}

// ---------------------------------------------------------------------------
// K3 (fused): per-row, one wave:
//  - exact 256th-smallest via LDS radix-select (256 bins x up to 4 passes,
//    per-wave histogram; early-exit interval-max when count==1)
//  - threshold; logits = row @ Wg^T; softmax-3; stable top-p -> gates
//  - mask build + diag, masked row softmax, bf16 adjb write
// grid = ROWS/4 blocks of 256. Lane owns j = lane*8..+7.
// ---------------------------------------------------------------------------
__global__ __launch_bounds__(256) void k_select(const float* __restrict__ adj,
        const float* __restrict__ Wg, const float* __restrict__ masks,
        ushort* __restrict__ adjb,
        float* __restrict__ spbuf, float* __restrict__ entbuf) {
    __shared__ int hist[4][256];
    int tid = threadIdx.x;
    int wave = tid >> 6, lane = tid & 63;
    int row = blockIdx.x * 4 + wave;
    int i = row & (kL - 1);
    const float* arow = adj + (size_t)row * kL;
    int* hw = hist[wave];
    int j0 = lane * 8;

    float v[8];
    {
        float4 a0 = *(const float4*)&arow[j0];
        float4 a1 = *(const float4*)&arow[j0 + 4];
        v[0] = a0.x; v[1] = a0.y; v[2] = a0.z; v[3] = a0.w;
        v[4] = a1.x; v[5] = a1.y; v[6] = a1.z; v[7] = a1.w;
    }
    unsigned key[8];
    #pragma unroll
    for (int t = 0; t < 8; ++t) {
        unsigned u = __float_as_uint(v[t]);
        key[t] = (u & 0x80000000u) ? ~u : (u | 0x80000000u);
    }

    // exact k-th smallest (k=255 0-indexed): radix select, 8 bits/pass.
    unsigned prefix = 0;
    int kk = 255;
    unsigned kth = 0;
    bool found = false;
    #pragma unroll 1
    for (int pass = 0; pass < 4; ++pass) {
        int shift = 24 - 8 * pass;
        *(int4*)&hw[lane * 4] = make_int4(0, 0, 0, 0);
        __asm__ volatile("s_waitcnt lgkmcnt(0)" ::: "memory");
        #pragma unroll
        for (int t = 0; t < 8; ++t) {
            bool pm = (pass == 0) || (((key[t] ^ prefix) >> (shift + 8)) == 0);
            if (pm) atomicAdd(&hw[(key[t] >> shift) & 255], 1);
        }
        __asm__ volatile("s_waitcnt lgkmcnt(0)" ::: "memory");
        int4 c = *(const int4*)&hw[lane * 4];
        int s0 = c.x + c.y + c.z + c.w;
        int incl = s0;
        #pragma unroll
        for (int off = 1; off < 64; off <<= 1) {
            int n = __shfl_up(incl, off);
            if (lane >= off) incl += n;
        }
        int excl = incl - s0;
        bool hit = (kk >= excl) && (kk < excl + s0);
        unsigned long long mb = __ballot(hit);
        int src = __ffsll((unsigned long long)mb) - 1;
        int b01 = c.x + c.y, b012 = b01 + c.z;
        int kloc = kk - excl;
        int d2, krem, cnt;
        if (kloc < c.x)      { d2 = 0; krem = kloc;        cnt = c.x; }
        else if (kloc < b01) { d2 = 1; krem = kloc - c.x;  cnt = c.y; }
        else if (kloc < b012){ d2 = 2; krem = kloc - b01;  cnt = c.z; }
        else                 { d2 = 3; krem = kloc - b012; cnt = c.w; }
        int packed = ((lane * 4 + d2) << 20) | (cnt << 10) | krem;
        packed = __shfl(packed, src);
        prefix |= (unsigned)((packed >> 20) & 0xFF) << shift;
        kk = packed & 0x3FF;
        int remain = (packed >> 10) & 0x3FF;
        if (remain == 1 && pass < 3) {
            // unique key in [prefix, prefix + 2^shift): extract by interval max
            unsigned w = 1u << shift;
            unsigned kx = 0;
            #pragma unroll
            for (int t = 0; t < 8; ++t) {
                unsigned d = key[t] - prefix;
                if (d < w) kx = max(kx, key[t]);
            }
            #pragma unroll
            for (int off = 1; off < 64; off <<= 1)
                kx = max(kx, (unsigned)__shfl_xor((int)kx, off));
            kth = kx;
            found = true;
            break;
        }
    }
    if (!found) kth = prefix;   // after 4 passes, prefix is the exact key
    float thr = (kth & 0x80000000u) ? __uint_as_float(kth & 0x7fffffffu)
                                    : __uint_as_float(~kth);

    // threshold + logits
    float l0 = 0.f, l1 = 0.f, l2 = 0.f;
    #pragma unroll
    for (int t = 0; t < 8; ++t) {
        float nv = (v[t] > thr) ? v[t] : 0.0f;
        v[t] = nv;
        int j = j0 + t;
        l0 = fmaf(nv, Wg[j], l0);
        l1 = fmaf(nv, Wg[kL + j], l1);
        l2 = fmaf(nv, Wg[2 * kL + j], l2);
    }
    #pragma unroll
    for (int off = 1; off < 64; off <<= 1) {
        l0 += __shfl_xor(l0, off);
        l1 += __shfl_xor(l1, off);
        l2 += __shfl_xor(l2, off);
    }
    // softmax-3 + stable top-p (all lanes redundantly; wave-uniform)
    float m = fmaxf(l0, fmaxf(l1, l2));
    float e0 = __expf(l0 - m), e1 = __expf(l1 - m), e2 = __expf(l2 - m);
    float s = e0 + e1 + e2;
    float p[3] = {e0 / s, e1 / s, e2 / s};
    int o0, o1, o2;
    if (p[0] >= p[1] && p[0] >= p[2]) o0 = 0;
    else if (p[1] >= p[2]) o0 = 1;
    else o0 = 2;
    int r0 = (o0 == 0) ? 1 : 0;
    int r1 = (o0 == 2) ? 1 : 2;
    if (p[r0] >= p[r1]) { o1 = r0; o2 = r1; } else { o1 = r1; o2 = r0; }
    float sp0 = p[o0], sp1 = p[o1], sp2 = p[o2];
    float c0 = sp0, c1 = sp0 + sp1, c2 = c1 + sp2;
    bool m0 = c0 > 0.5f, m1 = c1 > 0.5f, m2 = c2 > 0.5f;
    int ti = m0 ? 0 : (m1 ? 1 : 2);
    bool mm0 = m0 && (ti != 0);
    bool mm1 = m1 && (ti != 1);
    bool mm2 = m2 && (ti != 2);
    float g[3] = {0.f, 0.f, 0.f};
    g[o0] = mm0 ? 0.f : 1.f;
    g[o1] = mm1 ? 0.f : 1.f;
    g[o2] = mm2 ? 0.f : 1.f;
    if (lane == 0) {
        spbuf[row * 3 + 0] = mm0 ? 0.f : sp0;
        spbuf[row * 3 + 1] = mm1 ? 0.f : sp1;
        spbuf[row * 3 + 2] = mm2 ? 0.f : sp2;
        entbuf[row] = p[0] * __logf(p[0] + 1e-10f) +
                      p[1] * __logf(p[1] + 1e-10f) +
                      p[2] * __logf(p[2] + 1e-10f);
    }

    // mask build + diag, apply to thresholded values
    const float* mk0 = masks + (i * 3 + 0) * kL + j0;
    const float* mk1 = masks + (i * 3 + 1) * kL + j0;
    const float* mk2 = masks + (i * 3 + 2) * kL + j0;
    float av[8];
    #pragma unroll
    for (int half = 0; half < 2; ++half) {
        float4 v0 = *(const float4*)&mk0[half * 4];
        float4 v1 = *(const float4*)&mk1[half * 4];
        float4 v2 = *(const float4*)&mk2[half * 4];
        float mv[4];
        mv[0] = g[0] * v0.x + g[1] * v1.x + g[2] * v2.x;
        mv[1] = g[0] * v0.y + g[1] * v1.y + g[2] * v2.y;
        mv[2] = g[0] * v0.z + g[1] * v1.z + g[2] * v2.z;
        mv[3] = g[0] * v0.w + g[1] * v1.w + g[2] * v2.w;
        #pragma unroll
        for (int t = 0; t < 4; ++t) {
            int j = j0 + half * 4 + t;
            float mm = mv[t] + ((j == i) ? 1.0f : 0.0f);
            av[half * 4 + t] = v[half * 4 + t] * mm;
        }
    }
    // masked row softmax (post-softmax row sums to 1 +- 1e-7; the reference's
    // L1 renorm divides by that sum -- 4 orders below bf16 store rounding, skip)
    float mx = av[0];
    #pragma unroll
    for (int t = 1; t < 8; ++t) mx = fmaxf(mx, av[t]);
    #pragma unroll
    for (int off = 1; off < 64; off <<= 1) mx = fmaxf(mx, __shfl_xor(mx, off));
    float e[8], ls = 0.f;
    #pragma unroll
    for (int t = 0; t < 8; ++t) { e[t] = __expf(av[t] - mx); ls += e[t]; }
    #pragma unroll
    for (int off = 1; off < 64; off <<= 1) ls += __shfl_xor(ls, off);
    float inv = 1.0f / ls;
    union { ushort u[8]; int4 vv; } pk;
    #pragma unroll
    for (int t = 0; t < 8; ++t) pk.u[t] = f2bf(e[t] * inv);
    *(int4*)&adjb[(size_t)row * kL + j0] = pk.vv;
}

// ---------------------------------------------------------------------------
// K4 (MFMA, bf16): xp = x @ Wp^T + bp, written TRANSPOSED bf16:
// xpbT[dcol][b*L + l]. fp32->bf16 conversion in staging; transposed store
// comes free from the C-fragment layout (4 consecutive rows per lane).
// ---------------------------------------------------------------------------
__global__ __launch_bounds__(256) void k_xp(const float* __restrict__ x,
        const float* __restrict__ Wp, const float* __restrict__ bp,
        ushort* __restrict__ xpbT) {
    int it = blockIdx.x >> 3, jt = blockIdx.x & 7;   // it: l-rows, jt: d-cols
    __shared__ ushort xbs[64][72];
    __shared__ ushort wbs[64][72];
    int tid = threadIdx.x;
    int r = tid >> 2, s = tid & 3;
    int lane = tid & 63, wave = tid >> 6;
    int wm = wave >> 1, wn = wave & 1;
    int am = wm * 32 + (lane & 15);
    int bn = wn * 32 + (lane & 15);
    int coff = (lane >> 4) * 8;
    f32x4 acc[2][2] = {};
    const float* xsrc = x + (size_t)(it * 64 + r) * kD + s * 16;
    const float* wsrc = Wp + (size_t)(jt * 64 + r) * kD + s * 16;
    for (int kt = 0; kt < 8; ++kt) {
        union { ushort u[16]; int4 v[2]; } px, pw;
        #pragma unroll
        for (int c4 = 0; c4 < 4; ++c4) {
            float4 fx = *(const float4*)(xsrc + kt * 64 + c4 * 4);
            float4 fw = *(const float4*)(wsrc + kt * 64 + c4 * 4);
            px.u[c4 * 4 + 0] = f2bf(fx.x); px.u[c4 * 4 + 1] = f2bf(fx.y);
            px.u[c4 * 4 + 2] = f2bf(fx.z); px.u[c4 * 4 + 3] = f2bf(fx.w);
            pw.u[c4 * 4 + 0] = f2bf(fw.x); pw.u[c4 * 4 + 1] = f2bf(fw.y);
            pw.u[c4 * 4 + 2] = f2bf(fw.z); pw.u[c4 * 4 + 3] = f2bf(fw.w);
        }
        __syncthreads();
        *(int4*)&xbs[r][s * 16] = px.v[0];
        *(int4*)&xbs[r][s * 16 + 8] = px.v[1];
        *(int4*)&wbs[r][s * 16] = pw.v[0];
        *(int4*)&wbs[r][s * 16 + 8] = pw.v[1];
        __syncthreads();
        #pragma unroll
        for (int kk = 0; kk < 2; ++kk) {
            bf16x8 af[2], bf[2];
            #pragma unroll
            for (int fm = 0; fm < 2; ++fm)
                af[fm] = *(const bf16x8*)&xbs[am + fm * 16][kk * 32 + coff];
            #pragma unroll
            for (int fn = 0; fn < 2; ++fn)
                bf[fn] = *(const bf16x8*)&wbs[bn + fn * 16][kk * 32 + coff];
            #pragma unroll
            for (int fm = 0; fm < 2; ++fm)
                #pragma unroll
                for (int fn = 0; fn < 2; ++fn)
                    acc[fm][fn] = __builtin_amdgcn_mfma_f32_16x16x32_bf16(
                        af[fm], bf[fn], acc[fm][fn], 0, 0, 0);
        }
    }
    // epilogue: add bias, store transposed (4 consecutive l per lane)
    #pragma unroll
    for (int fn = 0; fn < 2; ++fn) {
        int dcol = jt * 64 + wn * 32 + (lane & 15) + fn * 16;
        float bpv = bp[dcol];
        #pragma unroll
        for (int fm = 0; fm < 2; ++fm) {
            int l0 = it * 64 + wm * 32 + fm * 16 + (lane >> 4) * 4;
            union { ushort u[4]; uint2 v; } pk;
            #pragma unroll
            for (int rr = 0; rr < 4; ++rr)
                pk.u[rr] = f2bf(acc[fm][fn][rr] + bpv);
            *(uint2*)&xpbT[(size_t)dcol * (size_t)(kB * kL) + l0] = pk.v;
        }
    }
}

// ---------------------------------------------------------------------------
// K6 (MFMA): out[b, i, h*64+d] = sum_j adjb[bh,i,j] * xpbT[h*64+d][b*512+j]
// ---------------------------------------------------------------------------
__global__ __launch_bounds__(256) void k_out(const ushort* __restrict__ adjb,
        const ushort* __restrict__ xpbT, float* __restrict__ out) {
    int blk = blockIdx.x;
    int bh = blk >> 3, it = blk & 7;
    int b = bh >> 3, h = bh & 7;
    __shared__ ushort as_[64][72];
    __shared__ ushort bs_[64][72];
    int tid = threadIdx.x;
    int lane = tid & 63, wave = tid >> 6;
    int wm = wave >> 1, wn = wave & 1;
    int r = tid >> 2, s = tid & 3;
    const ushort* aG = adjb + ((size_t)(bh * kL + it * 64 + r)) * kL + s * 16;
    const ushort* bG = xpbT + ((size_t)(h * kDH + r)) * (size_t)(kB * kL) + b * kL + s * 16;
    f32x4 acc[2][2] = {};
    int am = wm * 32 + (lane & 15);
    int bn = wn * 32 + (lane & 15);
    int coff = (lane >> 4) * 8;
    for (int kt = 0; kt < 8; ++kt) {
        int4 a0 = *(const int4*)(aG + kt * 64);
        int4 a1 = *(const int4*)(aG + kt * 64 + 8);
        int4 b0 = *(const int4*)(bG + kt * 64);
        int4 b1 = *(const int4*)(bG + kt * 64 + 8);
        __syncthreads();
        *(int4*)&as_[r][s * 16] = a0;
        *(int4*)&as_[r][s * 16 + 8] = a1;
        *(int4*)&bs_[r][s * 16] = b0;
        *(int4*)&bs_[r][s * 16 + 8] = b1;
        __syncthreads();
        #pragma unroll
        for (int kk = 0; kk < 2; ++kk) {
            bf16x8 af[2], bf[2];
            #pragma unroll
            for (int fm = 0; fm < 2; ++fm)
                af[fm] = *(const bf16x8*)&as_[am + fm * 16][kk * 32 + coff];
            #pragma unroll
            for (int fn = 0; fn < 2; ++fn)
                bf[fn] = *(const bf16x8*)&bs_[bn + fn * 16][kk * 32 + coff];
            #pragma unroll
            for (int fm = 0; fm < 2; ++fm)
                #pragma unroll
                for (int fn = 0; fn < 2; ++fn)
                    acc[fm][fn] = __builtin_amdgcn_mfma_f32_16x16x32_bf16(
                        af[fm], bf[fn], acc[fm][fn], 0, 0, 0);
        }
    }
    int mrow = it * 64 + wm * 32 + (lane >> 4) * 4;
    int ncol = h * kDH + wn * 32 + (lane & 15);
    #pragma unroll
    for (int fm = 0; fm < 2; ++fm)
        #pragma unroll
        for (int fn = 0; fn < 2; ++fn)
            #pragma unroll
            for (int rr = 0; rr < 4; ++rr)
                out[((size_t)b * kL + mrow + fm * 16 + rr) * kD + ncol + fn * 16] =
                    acc[fm][fn][rr];
}

// ---------------------------------------------------------------------------
// K7: finalize loss (single block, deterministic reductions)
// ---------------------------------------------------------------------------
__global__ __launch_bounds__(1024) void k_loss(const float* __restrict__ spbuf,
        const float* __restrict__ entbuf, float* __restrict__ out_loss) {
    __shared__ float imps[kL * 3];
    __shared__ float red[1024];
    int tid = threadIdx.x;
    for (int idx = tid; idx < kL * 3; idx += 1024) {
        float s = 0.f;
        for (int bh = 0; bh < kBH; ++bh)
            s += spbuf[bh * kL * 3 + idx];
        imps[idx] = s;
    }
    float es = 0.f;
    for (int idx = tid; idx < kROWS; idx += 1024) es += entbuf[idx];
    red[tid] = es;
    __syncthreads();
    for (int s = 512; s > 0; s >>= 1) {
        if (tid < s) red[tid] += red[tid + s];
        __syncthreads();
    }
    float ent_total = red[0];
    __syncthreads();
    float ms = 0.f;
    for (int idx = tid; idx < kL * 3; idx += 1024) ms += imps[idx];
    red[tid] = ms;
    __syncthreads();
    for (int s = 512; s > 0; s >>= 1) {
        if (tid < s) red[tid] += red[tid + s];
        __syncthreads();
    }
    float mean = red[0] / (float)(kL * 3);
    __syncthreads();
    float vs = 0.f;
    for (int idx = tid; idx < kL * 3; idx += 1024) {
        float d = imps[idx] - mean;
        vs += d * d;
    }
    red[tid] = vs;
    __syncthreads();
    for (int s = 512; s > 0; s >>= 1) {
        if (tid < s) red[tid] += red[tid + s];
        __syncthreads();
    }
    if (tid == 0) {
        float var = red[0] / (float)(kL * 3 - 1);
        float loss_imp = var / (mean * mean + 1e-10f);
        float loss_dyn = -ent_total / (float)(kBH * 3);
        out_loss[0] = loss_imp + 0.1f * loss_dyn;
    }
}

// ---------------------------------------------------------------------------
extern "C" void kernel_launch(void* const* d_in, const int* in_sizes, int n_in,
                              void* d_out, int out_size, void* d_ws, size_t ws_size,
                              hipStream_t stream) {
    const float* x     = (const float*)d_in[0];
    const float* masks = (const float*)d_in[1];
    const float* W1    = (const float*)d_in[2];
    const float* b1    = (const float*)d_in[3];
    const float* W2    = (const float*)d_in[4];
    const float* b2    = (const float*)d_in[5];
    const float* Wg    = (const float*)d_in[6];
    const float* Wp    = (const float*)d_in[7];
    const float* bp    = (const float*)d_in[8];
    float* out = (float*)d_out;
    float* ws  = (float*)d_ws;

    // workspace layout (float units). adjb overlays qh/ql/kh/kl (dead after
    // k_adj; stream order serializes k_adj -> k_select).
    float*  adj   = ws;                          // [0, 16777216)
    ushort* qh    = (ushort*)(ws + 16777216);    // 2,097,152 ushorts (1.05M f)
    ushort* ql    = (ushort*)(ws + 17825792);
    ushort* kh    = (ushort*)(ws + 18874368);
    ushort* kl    = (ushort*)(ws + 19922944);
    ushort* adjb  = (ushort*)(ws + 16777216);    // overlays qh..kl + extra
    ushort* xpbT  = (ushort*)(ws + 25165824);
    float*  spbuf = ws + 26214400;               // 98,304
    float*  entbuf= ws + 26312704;               // 32,768

    k_qk<<<512, 256, 0, stream>>>(x, W1, b1, W2, b2, qh, ql, kh, kl);
    k_adj<<<kBH * 64, 256, 0, stream>>>(qh, ql, kh, kl, adj);
    k_select<<<kROWS / 4, 256, 0, stream>>>(adj, Wg, masks, adjb, spbuf, entbuf);
    k_xp<<<512, 256, 0, stream>>>(x, Wp, bp, xpbT);
    k_out<<<512, 256, 0, stream>>>(adjb, xpbT, out);
    k_loss<<<1, 1024, 0, stream>>>(spbuf, entbuf, out + (size_t)kB * kL * kD);
}

// Round 10
// 127.483 us; speedup vs baseline: 1.0240x; 1.0240x over previous
//
#include <hip/hip_runtime.h>
#include <hip/hip_bf16.h>
#include <math.h>

// Problem constants
static constexpr int kB = 8;
static constexpr int kH = 8;
static constexpr int kL = 512;
static constexpr int kD = 512;
static constexpr int kDH = 64;     // D/H
static constexpr int kBH = 64;     // B*H
static constexpr int kROWS = kBH * kL;  // 32768

typedef short bf16x8 __attribute__((ext_vector_type(8)));
typedef float f32x4 __attribute__((ext_vector_type(4)));

// RNE float->bf16 (finite inputs only)
__device__ __forceinline__ ushort f2bf(float f) {
    unsigned u = __float_as_uint(f);
    unsigned r = u + 0x7fffu + ((u >> 16) & 1u);
    return (ushort)(r >> 16);
}
__device__ __forceinline__ float bf2f(ushort h) {
    return __uint_as_float((unsigned)h << 16);
}
// order-isomorphic float<->uint maps (finite, no NaN; -0.0 < +0.0 in key order)
__device__ __forceinline__ unsigned mapf(float f) {
    unsigned u = __float_as_uint(f);
    return (u & 0x80000000u) ? ~u : (u | 0x80000000u);
}
__device__ __forceinline__ float unmapf(unsigned u) {
    return (u & 0x80000000u) ? __uint_as_float(u ^ 0x80000000u)
                             : __uint_as_float(~u);
}

// gelu with A&S 7.1.26 erf (max abs err ~1.5e-7, monotone-preserving)
__device__ __forceinline__ float gelu_fast(float v) {
    float z = v * 0.70710678118654752440f;
    float az = fabsf(z);
    float t = 1.0f / (1.0f + 0.3275911f * az);
    float ex = __expf(-az * az);
    float poly = t * (0.254829592f + t * (-0.284496736f + t * (1.421413741f +
                 t * (-1.453152027f + t * 1.061405429f))));
    float erfv = 1.0f - poly * ex;
    erfv = (z < 0.0f) ? -erfv : erfv;
    return 0.5f * v * (1.0f + erfv);
}

// ---------------------------------------------------------------------------
// K1: q = xh@W1^T + b1, k = xh@W2^T + b2 as tiled GEMM (fp32 FMA).
// Epilogue writes hi/lo bf16 pairs directly.
// ---------------------------------------------------------------------------
__global__ __launch_bounds__(256) void k_qk(const float* __restrict__ x,
        const float* __restrict__ W1, const float* __restrict__ b1,
        const float* __restrict__ W2, const float* __restrict__ b2,
        ushort* __restrict__ qh, ushort* __restrict__ ql,
        ushort* __restrict__ kh, ushort* __restrict__ kl) {
    int blk = blockIdx.x;              // b*64 + h*8 + lt
    int b = blk >> 6, h = (blk >> 3) & 7, lt = blk & 7;
    __shared__ float xt[64][68];       // [l][c]
    __shared__ float w1t[64][68];      // [d][c]
    __shared__ float w2t[64][68];
    int tid = threadIdx.x;
    #pragma unroll
    for (int r = 0; r < 16; ++r) {
        int e = tid + r * 256;
        int rr = e >> 6, cc = e & 63;
        xt[rr][cc]  = x[(b * kL + lt * 64 + rr) * kD + h * kDH + cc];
        w1t[rr][cc] = W1[rr * 64 + cc];
        w2t[rr][cc] = W2[rr * 64 + cc];
    }
    __syncthreads();
    int ty = tid >> 4, tx = tid & 15;
    float aq[4][4] = {}, ak[4][4] = {};
    #pragma unroll 2
    for (int c = 0; c < 64; c += 4) {
        float4 av[4], wq[4], wk[4];
        #pragma unroll
        for (int a = 0; a < 4; ++a) av[a] = *(const float4*)&xt[ty * 4 + a][c];
        #pragma unroll
        for (int j = 0; j < 4; ++j) {
            wq[j] = *(const float4*)&w1t[tx + 16 * j][c];
            wk[j] = *(const float4*)&w2t[tx + 16 * j][c];
        }
        #pragma unroll
        for (int a = 0; a < 4; ++a)
            #pragma unroll
            for (int j = 0; j < 4; ++j) {
                aq[a][j] = fmaf(av[a].x, wq[j].x, aq[a][j]);
                aq[a][j] = fmaf(av[a].y, wq[j].y, aq[a][j]);
                aq[a][j] = fmaf(av[a].z, wq[j].z, aq[a][j]);
                aq[a][j] = fmaf(av[a].w, wq[j].w, aq[a][j]);
                ak[a][j] = fmaf(av[a].x, wk[j].x, ak[a][j]);
                ak[a][j] = fmaf(av[a].y, wk[j].y, ak[a][j]);
                ak[a][j] = fmaf(av[a].z, wk[j].z, ak[a][j]);
                ak[a][j] = fmaf(av[a].w, wk[j].w, ak[a][j]);
            }
    }
    #pragma unroll
    for (int a = 0; a < 4; ++a)
        #pragma unroll
        for (int j = 0; j < 4; ++j) {
            int row = lt * 64 + ty * 4 + a;
            int col = tx + 16 * j;
            int o = ((b * kH + h) * kL + row) * kDH + col;
            float qv = aq[a][j] + b1[col];
            float kv = ak[a][j] + b2[col];
            ushort qhh = f2bf(qv), khh = f2bf(kv);
            qh[o] = qhh; ql[o] = f2bf(qv - bf2f(qhh));
            kh[o] = khh; kl[o] = f2bf(kv - bf2f(khh));
        }
}

// ---------------------------------------------------------------------------
// K2 (MFMA, split-bf16): adj = gelu(q @ k^T) per (b,h). 64x64 tile, K=64.
// ---------------------------------------------------------------------------
__global__ __launch_bounds__(256) void k_adj(const ushort* __restrict__ qh,
        const ushort* __restrict__ ql, const ushort* __restrict__ kh,
        const ushort* __restrict__ kl, float* __restrict__ adj) {
    int blk = blockIdx.x;
    int bh = blk >> 6;
    int it = (blk >> 3) & 7, jt = blk & 7;
    __shared__ ushort ah[64][72], al[64][72];
    __shared__ ushort bh_[64][72], bl[64][72];
    int tid = threadIdx.x;
    int r = tid >> 2, s = tid & 3;
    size_t aoff = (size_t)(bh * kL + it * 64 + r) * kDH + s * 16;
    size_t boff = (size_t)(bh * kL + jt * 64 + r) * kDH + s * 16;
    *(int4*)&ah[r][s * 16]  = *(const int4*)&qh[aoff];
    *(int4*)&ah[r][s * 16 + 8]  = *(const int4*)&qh[aoff + 8];
    *(int4*)&al[r][s * 16]  = *(const int4*)&ql[aoff];
    *(int4*)&al[r][s * 16 + 8]  = *(const int4*)&ql[aoff + 8];
    *(int4*)&bh_[r][s * 16] = *(const int4*)&kh[boff];
    *(int4*)&bh_[r][s * 16 + 8] = *(const int4*)&kh[boff + 8];
    *(int4*)&bl[r][s * 16]  = *(const int4*)&kl[boff];
    *(int4*)&bl[r][s * 16 + 8]  = *(const int4*)&kl[boff + 8];
    __syncthreads();
    int lane = tid & 63, wave = tid >> 6;
    int wm = wave >> 1, wn = wave & 1;
    int am = wm * 32 + (lane & 15);
    int bn = wn * 32 + (lane & 15);
    int coff = (lane >> 4) * 8;
    f32x4 acc[2][2] = {};
    #pragma unroll
    for (int kk = 0; kk < 2; ++kk) {
        bf16x8 afh[2], afl[2], bfh[2], bfl[2];
        #pragma unroll
        for (int fm = 0; fm < 2; ++fm) {
            afh[fm] = *(const bf16x8*)&ah[am + fm * 16][kk * 32 + coff];
            afl[fm] = *(const bf16x8*)&al[am + fm * 16][kk * 32 + coff];
        }
        #pragma unroll
        for (int fn = 0; fn < 2; ++fn) {
            bfh[fn] = *(const bf16x8*)&bh_[bn + fn * 16][kk * 32 + coff];
            bfl[fn] = *(const bf16x8*)&bl[bn + fn * 16][kk * 32 + coff];
        }
        #pragma unroll
        for (int fm = 0; fm < 2; ++fm)
            #pragma unroll
            for (int fn = 0; fn < 2; ++fn) {
                acc[fm][fn] = __builtin_amdgcn_mfma_f32_16x16x32_bf16(
                    afh[fm], bfh[fn], acc[fm][fn], 0, 0, 0);
                acc[fm][fn] = __builtin_amdgcn_mfma_f32_16x16x32_bf16(
                    afh[fm], bfl[fn], acc[fm][fn], 0, 0, 0);
                acc[fm][fn] = __builtin_amdgcn_mfma_f32_16x16x32_bf16(
                    afl[fm], bfh[fn], acc[fm][fn], 0, 0, 0);
            }
    }
    int mrow = it * 64 + wm * 32 + (lane >> 4) * 4;
    int ncol = jt * 64 + wn * 32 + (lane & 15);
    #pragma unroll
    for (int fm = 0; fm < 2; ++fm)
        #pragma unroll
        for (int fn = 0; fn < 2; ++fn)
            #pragma unroll
            for (int rr = 0; rr < 4; ++rr)
                adj[((size_t)bh * kL + mrow + fm * 16 + rr) * kL + ncol + fn * 16] =
                    gelu_fast(acc[fm][fn][rr]);
}

// ---------------------------------------------------------------------------
// K3 (fused): per-row, one wave. Exact 256th-smallest via ballot bisection
// ENTIRELY in integer key space (round-9 fix: gelu emits -0.0; float-domain
// counting at cand=+0.0 undercounts -0.0s and derails the bisection).
// Prefix-skip from wave min/max, boundary early-exits, integer extraction.
// Then threshold, logits, softmax-3, top-p, computed masks, row softmax,
// bf16 adjb write. grid = ROWS/4 blocks of 256.
// ---------------------------------------------------------------------------
__global__ __launch_bounds__(256) void k_select(const float* __restrict__ adj,
        const float* __restrict__ Wg,
        ushort* __restrict__ adjb,
        float* __restrict__ spbuf, float* __restrict__ entbuf) {
    int tid = threadIdx.x;
    int wave = tid >> 6, lane = tid & 63;
    int row = blockIdx.x * 4 + wave;
    int i = row & (kL - 1);
    const float* arow = adj + (size_t)row * kL;
    int j0 = lane * 8;

    float v[8];
    {
        float4 a0 = *(const float4*)&arow[j0];
        float4 a1 = *(const float4*)&arow[j0 + 4];
        v[0] = a0.x; v[1] = a0.y; v[2] = a0.z; v[3] = a0.w;
        v[4] = a1.x; v[5] = a1.y; v[6] = a1.z; v[7] = a1.w;
    }
    unsigned key[8];
    #pragma unroll
    for (int t = 0; t < 8; ++t) key[t] = mapf(v[t]);

    // wave min/max keys for prefix skip
    unsigned kmn = key[0], kmx = key[0];
    #pragma unroll
    for (int t = 1; t < 8; ++t) { kmn = min(kmn, key[t]); kmx = max(kmx, key[t]); }
    #pragma unroll
    for (int off = 1; off < 64; off <<= 1) {
        kmn = min(kmn, (unsigned)__shfl_xor((int)kmn, off));
        kmx = max(kmx, (unsigned)__shfl_xor((int)kmx, off));
    }

    float thr;
    if (kmn == kmx) {
        thr = unmapf(kmn);              // all 512 values identical
    } else {
        int b0 = 31 - __clz(kmn ^ kmx); // first differing bit
        unsigned hm = (b0 >= 31) ? 0u : ~((1u << (b0 + 1)) - 1u);
        unsigned prefix = kmn & hm;     // common prefix
        int bit = b0;
        int cbp = 0, cin = 512;
        int mode = 0;                   // 0: exhausted, 1: extract-min, 2: extract-max
        while (bit >= 0) {
            unsigned cand = prefix | (1u << bit);
            int c = 0;
            #pragma unroll
            for (int t = 0; t < 8; ++t)
                c += (int)__popcll(__ballot(key[t] < cand));
            if (255 < c) {
                cin = c - cbp;
            } else {
                cin -= (c - cbp);
                prefix = cand;
                cbp = c;
            }
            --bit;
            int loc = 255 - cbp;        // local rank of kth within interval
            if (cin == 1)        { mode = 2; break; }
            if (loc == 0)        { mode = 1; break; }
            if (loc == cin - 1)  { mode = 2; break; }
        }
        if (mode == 0) {
            thr = unmapf(prefix);       // duplicates: prefix is the exact key
        } else {
            // integer-domain membership: d = key - prefix < width
            unsigned width = 1u << (bit + 1);   // bit in [-1,30]
            unsigned acc = (mode == 1) ? 0xFFFFFFFFu : 0u;
            #pragma unroll
            for (int t = 0; t < 8; ++t) {
                unsigned d = key[t] - prefix;
                bool mem = d < width;
                if (mode == 1) acc = (mem && key[t] < acc) ? key[t] : acc;
                else           acc = (mem && key[t] > acc) ? key[t] : acc;
            }
            if (mode == 1) {
                #pragma unroll
                for (int off = 1; off < 64; off <<= 1)
                    acc = min(acc, (unsigned)__shfl_xor((int)acc, off));
            } else {
                #pragma unroll
                for (int off = 1; off < 64; off <<= 1)
                    acc = max(acc, (unsigned)__shfl_xor((int)acc, off));
            }
            thr = unmapf(acc);
        }
    }

    // threshold + logits (Wg as float4)
    union { float4 f4[2]; float f[8]; } wg0, wg1, wg2;
    wg0.f4[0] = *(const float4*)&Wg[j0];          wg0.f4[1] = *(const float4*)&Wg[j0 + 4];
    wg1.f4[0] = *(const float4*)&Wg[kL + j0];     wg1.f4[1] = *(const float4*)&Wg[kL + j0 + 4];
    wg2.f4[0] = *(const float4*)&Wg[2 * kL + j0]; wg2.f4[1] = *(const float4*)&Wg[2 * kL + j0 + 4];
    float l0 = 0.f, l1 = 0.f, l2 = 0.f;
    #pragma unroll
    for (int t = 0; t < 8; ++t) {
        float nv = (v[t] > thr) ? v[t] : 0.0f;
        v[t] = nv;
        l0 = fmaf(nv, wg0.f[t], l0);
        l1 = fmaf(nv, wg1.f[t], l1);
        l2 = fmaf(nv, wg2.f[t], l2);
    }
    #pragma unroll
    for (int off = 1; off < 64; off <<= 1) {
        l0 += __shfl_xor(l0, off);
        l1 += __shfl_xor(l1, off);
        l2 += __shfl_xor(l2, off);
    }
    // softmax-3 + stable top-p (all lanes redundantly; wave-uniform)
    float m = fmaxf(l0, fmaxf(l1, l2));
    float e0 = __expf(l0 - m), e1 = __expf(l1 - m), e2 = __expf(l2 - m);
    float s = e0 + e1 + e2;
    float p[3] = {e0 / s, e1 / s, e2 / s};
    int o0, o1, o2;
    if (p[0] >= p[1] && p[0] >= p[2]) o0 = 0;
    else if (p[1] >= p[2]) o0 = 1;
    else o0 = 2;
    int r0 = (o0 == 0) ? 1 : 0;
    int r1 = (o0 == 2) ? 1 : 2;
    if (p[r0] >= p[r1]) { o1 = r0; o2 = r1; } else { o1 = r1; o2 = r0; }
    float sp0 = p[o0], sp1 = p[o1], sp2 = p[o2];
    float c0 = sp0, c1 = sp0 + sp1, c2 = c1 + sp2;
    bool m0 = c0 > 0.5f, m1 = c1 > 0.5f, m2 = c2 > 0.5f;
    int ti = m0 ? 0 : (m1 ? 1 : 2);
    bool mm0 = m0 && (ti != 0);
    bool mm1 = m1 && (ti != 1);
    bool mm2 = m2 && (ti != 2);
    float g[3] = {0.f, 0.f, 0.f};
    g[o0] = mm0 ? 0.f : 1.f;
    g[o1] = mm1 ? 0.f : 1.f;
    g[o2] = mm2 ? 0.f : 1.f;
    if (lane == 0) {
        spbuf[row * 3 + 0] = mm0 ? 0.f : sp0;
        spbuf[row * 3 + 1] = mm1 ? 0.f : sp1;
        spbuf[row * 3 + 2] = mm2 ? 0.f : sp2;
        entbuf[row] = p[0] * __logf(p[0] + 1e-10f) +
                      p[1] * __logf(p[1] + 1e-10f) +
                      p[2] * __logf(p[2] + 1e-10f);
    }

    // computed masks: S (same mod-64 residue, j!=i) -> g0; T (same 64-block,
    // incl diag) -> g1 (+1 on diag); else -> g2
    int i6 = i >> 6, i63 = i & 63;
    bool inb = ((lane >> 3) == i6);             // lane's 8 elems share j>>6
    float sel1 = inb ? (g[1] + 1.0f) : g[0];
    float sel0 = inb ? g[1] : g[2];
    int lane8 = (lane & 7) * 8;
    float av[8];
    #pragma unroll
    for (int t = 0; t < 8; ++t) {
        bool ing = (lane8 + t) == i63;
        av[t] = v[t] * (ing ? sel1 : sel0);
    }
    // masked row softmax (L1 renorm of a softmax row ~= identity; skipped)
    float mx = av[0];
    #pragma unroll
    for (int t = 1; t < 8; ++t) mx = fmaxf(mx, av[t]);
    #pragma unroll
    for (int off = 1; off < 64; off <<= 1) mx = fmaxf(mx, __shfl_xor(mx, off));
    float e[8], ls = 0.f;
    #pragma unroll
    for (int t = 0; t < 8; ++t) { e[t] = __expf(av[t] - mx); ls += e[t]; }
    #pragma unroll
    for (int off = 1; off < 64; off <<= 1) ls += __shfl_xor(ls, off);
    float inv = 1.0f / ls;
    union { ushort u[8]; int4 vv; } pk;
    #pragma unroll
    for (int t = 0; t < 8; ++t) pk.u[t] = f2bf(e[t] * inv);
    *(int4*)&adjb[(size_t)row * kL + j0] = pk.vv;
}

// ---------------------------------------------------------------------------
// K4 (MFMA, bf16): xp = x @ Wp^T + bp, written TRANSPOSED bf16:
// xpbT[dcol][b*L + l].
// ---------------------------------------------------------------------------
__global__ __launch_bounds__(256) void k_xp(const float* __restrict__ x,
        const float* __restrict__ Wp, const float* __restrict__ bp,
        ushort* __restrict__ xpbT) {
    int it = blockIdx.x >> 3, jt = blockIdx.x & 7;   // it: l-rows, jt: d-cols
    __shared__ ushort xbs[64][72];
    __shared__ ushort wbs[64][72];
    int tid = threadIdx.x;
    int r = tid >> 2, s = tid & 3;
    int lane = tid & 63, wave = tid >> 6;
    int wm = wave >> 1, wn = wave & 1;
    int am = wm * 32 + (lane & 15);
    int bn = wn * 32 + (lane & 15);
    int coff = (lane >> 4) * 8;
    f32x4 acc[2][2] = {};
    const float* xsrc = x + (size_t)(it * 64 + r) * kD + s * 16;
    const float* wsrc = Wp + (size_t)(jt * 64 + r) * kD + s * 16;
    for (int kt = 0; kt < 8; ++kt) {
        union { ushort u[16]; int4 v[2]; } px, pw;
        #pragma unroll
        for (int c4 = 0; c4 < 4; ++c4) {
            float4 fx = *(const float4*)(xsrc + kt * 64 + c4 * 4);
            float4 fw = *(const float4*)(wsrc + kt * 64 + c4 * 4);
            px.u[c4 * 4 + 0] = f2bf(fx.x); px.u[c4 * 4 + 1] = f2bf(fx.y);
            px.u[c4 * 4 + 2] = f2bf(fx.z); px.u[c4 * 4 + 3] = f2bf(fx.w);
            pw.u[c4 * 4 + 0] = f2bf(fw.x); pw.u[c4 * 4 + 1] = f2bf(fw.y);
            pw.u[c4 * 4 + 2] = f2bf(fw.z); pw.u[c4 * 4 + 3] = f2bf(fw.w);
        }
        __syncthreads();
        *(int4*)&xbs[r][s * 16] = px.v[0];
        *(int4*)&xbs[r][s * 16 + 8] = px.v[1];
        *(int4*)&wbs[r][s * 16] = pw.v[0];
        *(int4*)&wbs[r][s * 16 + 8] = pw.v[1];
        __syncthreads();
        #pragma unroll
        for (int kk = 0; kk < 2; ++kk) {
            bf16x8 af[2], bf[2];
            #pragma unroll
            for (int fm = 0; fm < 2; ++fm)
                af[fm] = *(const bf16x8*)&xbs[am + fm * 16][kk * 32 + coff];
            #pragma unroll
            for (int fn = 0; fn < 2; ++fn)
                bf[fn] = *(const bf16x8*)&wbs[bn + fn * 16][kk * 32 + coff];
            #pragma unroll
            for (int fm = 0; fm < 2; ++fm)
                #pragma unroll
                for (int fn = 0; fn < 2; ++fn)
                    acc[fm][fn] = __builtin_amdgcn_mfma_f32_16x16x32_bf16(
                        af[fm], bf[fn], acc[fm][fn], 0, 0, 0);
        }
    }
    // epilogue: add bias, store transposed (4 consecutive l per lane)
    #pragma unroll
    for (int fn = 0; fn < 2; ++fn) {
        int dcol = jt * 64 + wn * 32 + (lane & 15) + fn * 16;
        float bpv = bp[dcol];
        #pragma unroll
        for (int fm = 0; fm < 2; ++fm) {
            int l0 = it * 64 + wm * 32 + fm * 16 + (lane >> 4) * 4;
            union { ushort u[4]; uint2 v; } pk;
            #pragma unroll
            for (int rr = 0; rr < 4; ++rr)
                pk.u[rr] = f2bf(acc[fm][fn][rr] + bpv);
            *(uint2*)&xpbT[(size_t)dcol * (size_t)(kB * kL) + l0] = pk.v;
        }
    }
}

// ---------------------------------------------------------------------------
// K6 (MFMA): out[b, i, h*64+d] = sum_j adjb[bh,i,j] * xpbT[h*64+d][b*512+j]
// ---------------------------------------------------------------------------
__global__ __launch_bounds__(256) void k_out(const ushort* __restrict__ adjb,
        const ushort* __restrict__ xpbT, float* __restrict__ out) {
    int blk = blockIdx.x;
    int bh = blk >> 3, it = blk & 7;
    int b = bh >> 3, h = bh & 7;
    __shared__ ushort as_[64][72];
    __shared__ ushort bs_[64][72];
    int tid = threadIdx.x;
    int lane = tid & 63, wave = tid >> 6;
    int wm = wave >> 1, wn = wave & 1;
    int r = tid >> 2, s = tid & 3;
    const ushort* aG = adjb + ((size_t)(bh * kL + it * 64 + r)) * kL + s * 16;
    const ushort* bG = xpbT + ((size_t)(h * kDH + r)) * (size_t)(kB * kL) + b * kL + s * 16;
    f32x4 acc[2][2] = {};
    int am = wm * 32 + (lane & 15);
    int bn = wn * 32 + (lane & 15);
    int coff = (lane >> 4) * 8;
    for (int kt = 0; kt < 8; ++kt) {
        int4 a0 = *(const int4*)(aG + kt * 64);
        int4 a1 = *(const int4*)(aG + kt * 64 + 8);
        int4 b0 = *(const int4*)(bG + kt * 64);
        int4 b1 = *(const int4*)(bG + kt * 64 + 8);
        __syncthreads();
        *(int4*)&as_[r][s * 16] = a0;
        *(int4*)&as_[r][s * 16 + 8] = a1;
        *(int4*)&bs_[r][s * 16] = b0;
        *(int4*)&bs_[r][s * 16 + 8] = b1;
        __syncthreads();
        #pragma unroll
        for (int kk = 0; kk < 2; ++kk) {
            bf16x8 af[2], bf[2];
            #pragma unroll
            for (int fm = 0; fm < 2; ++fm)
                af[fm] = *(const bf16x8*)&as_[am + fm * 16][kk * 32 + coff];
            #pragma unroll
            for (int fn = 0; fn < 2; ++fn)
                bf[fn] = *(const bf16x8*)&bs_[bn + fn * 16][kk * 32 + coff];
            #pragma unroll
            for (int fm = 0; fm < 2; ++fm)
                #pragma unroll
                for (int fn = 0; fn < 2; ++fn)
                    acc[fm][fn] = __builtin_amdgcn_mfma_f32_16x16x32_bf16(
                        af[fm], bf[fn], acc[fm][fn], 0, 0, 0);
        }
    }
    int mrow = it * 64 + wm * 32 + (lane >> 4) * 4;
    int ncol = h * kDH + wn * 32 + (lane & 15);
    #pragma unroll
    for (int fm = 0; fm < 2; ++fm)
        #pragma unroll
        for (int fn = 0; fn < 2; ++fn)
            #pragma unroll
            for (int rr = 0; rr < 4; ++rr)
                out[((size_t)b * kL + mrow + fm * 16 + rr) * kD + ncol + fn * 16] =
                    acc[fm][fn][rr];
}

// ---------------------------------------------------------------------------
// K7: finalize loss (single block, deterministic reductions)
// ---------------------------------------------------------------------------
__global__ __launch_bounds__(1024) void k_loss(const float* __restrict__ spbuf,
        const float* __restrict__ entbuf, float* __restrict__ out_loss) {
    __shared__ float imps[kL * 3];
    __shared__ float red[1024];
    int tid = threadIdx.x;
    for (int idx = tid; idx < kL * 3; idx += 1024) {
        float s = 0.f;
        for (int bh = 0; bh < kBH; ++bh)
            s += spbuf[bh * kL * 3 + idx];
        imps[idx] = s;
    }
    float es = 0.f;
    for (int idx = tid; idx < kROWS; idx += 1024) es += entbuf[idx];
    red[tid] = es;
    __syncthreads();
    for (int s = 512; s > 0; s >>= 1) {
        if (tid < s) red[tid] += red[tid + s];
        __syncthreads();
    }
    float ent_total = red[0];
    __syncthreads();
    float ms = 0.f;
    for (int idx = tid; idx < kL * 3; idx += 1024) ms += imps[idx];
    red[tid] = ms;
    __syncthreads();
    for (int s = 512; s > 0; s >>= 1) {
        if (tid < s) red[tid] += red[tid + s];
        __syncthreads();
    }
    float mean = red[0] / (float)(kL * 3);
    __syncthreads();
    float vs = 0.f;
    for (int idx = tid; idx < kL * 3; idx += 1024) {
        float d = imps[idx] - mean;
        vs += d * d;
    }
    red[tid] = vs;
    __syncthreads();
    for (int s = 512; s > 0; s >>= 1) {
        if (tid < s) red[tid] += red[tid + s];
        __syncthreads();
    }
    if (tid == 0) {
        float var = red[0] / (float)(kL * 3 - 1);
        float loss_imp = var / (mean * mean + 1e-10f);
        float loss_dyn = -ent_total / (float)(kBH * 3);
        out_loss[0] = loss_imp + 0.1f * loss_dyn;
    }
}

// ---------------------------------------------------------------------------
extern "C" void kernel_launch(void* const* d_in, const int* in_sizes, int n_in,
                              void* d_out, int out_size, void* d_ws, size_t ws_size,
                              hipStream_t stream) {
    const float* x     = (const float*)d_in[0];
    const float* W1    = (const float*)d_in[2];
    const float* b1    = (const float*)d_in[3];
    const float* W2    = (const float*)d_in[4];
    const float* b2    = (const float*)d_in[5];
    const float* Wg    = (const float*)d_in[6];
    const float* Wp    = (const float*)d_in[7];
    const float* bp    = (const float*)d_in[8];
    float* out = (float*)d_out;
    float* ws  = (float*)d_ws;

    // workspace layout (float units). adjb overlays qh/ql/kh/kl (dead after
    // k_adj; stream order serializes k_adj -> k_select).
    float*  adj   = ws;                          // [0, 16777216)
    ushort* qh    = (ushort*)(ws + 16777216);
    ushort* ql    = (ushort*)(ws + 17825792);
    ushort* kh    = (ushort*)(ws + 18874368);
    ushort* kl    = (ushort*)(ws + 19922944);
    ushort* adjb  = (ushort*)(ws + 16777216);    // overlays qh..kl + extra
    ushort* xpbT  = (ushort*)(ws + 25165824);
    float*  spbuf = ws + 26214400;               // 98,304
    float*  entbuf= ws + 26312704;               // 32,768

    k_qk<<<512, 256, 0, stream>>>(x, W1, b1, W2, b2, qh, ql, kh, kl);
    k_adj<<<kBH * 64, 256, 0, stream>>>(qh, ql, kh, kl, adj);
    k_select<<<kROWS / 4, 256, 0, stream>>>(adj, Wg, adjb, spbuf, entbuf);
    k_xp<<<512, 256, 0, stream>>>(x, Wp, bp, xpbT);
    k_out<<<512, 256, 0, stream>>>(adjb, xpbT, out);
    k_loss<<<1, 1024, 0, stream>>>(spbuf, entbuf, out + (size_t)kB * kL * kD);
}

// Round 11
// 126.741 us; speedup vs baseline: 1.0300x; 1.0059x over previous
//
#include <hip/hip_runtime.h>
#include <hip/hip_bf16.h>
#include <math.h>

// Problem constants
static constexpr int kB = 8;
static constexpr int kH = 8;
static constexpr int kL = 512;
static constexpr int kD = 512;
static constexpr int kDH = 64;     // D/H
static constexpr int kBH = 64;     // B*H
static constexpr int kROWS = kBH * kL;  // 32768

typedef short bf16x8 __attribute__((ext_vector_type(8)));
typedef float f32x4 __attribute__((ext_vector_type(4)));

// RNE float->bf16 (finite inputs only)
__device__ __forceinline__ ushort f2bf(float f) {
    unsigned u = __float_as_uint(f);
    unsigned r = u + 0x7fffu + ((u >> 16) & 1u);
    return (ushort)(r >> 16);
}
__device__ __forceinline__ float bf2f(ushort h) {
    return __uint_as_float((unsigned)h << 16);
}
// order-isomorphic float<->uint maps (finite, no NaN; -0.0 < +0.0 in key order)
__device__ __forceinline__ unsigned mapf(float f) {
    unsigned u = __float_as_uint(f);
    return (u & 0x80000000u) ? ~u : (u | 0x80000000u);
}
__device__ __forceinline__ float unmapf(unsigned u) {
    return (u & 0x80000000u) ? __uint_as_float(u ^ 0x80000000u)
                             : __uint_as_float(~u);
}

// gelu with A&S 7.1.26 erf (max abs err ~1.5e-7, monotone-preserving)
__device__ __forceinline__ float gelu_fast(float v) {
    float z = v * 0.70710678118654752440f;
    float az = fabsf(z);
    float t = 1.0f / (1.0f + 0.3275911f * az);
    float ex = __expf(-az * az);
    float poly = t * (0.254829592f + t * (-0.284496736f + t * (1.421413741f +
                 t * (-1.453152027f + t * 1.061405429f))));
    float erfv = 1.0f - poly * ex;
    erfv = (z < 0.0f) ? -erfv : erfv;
    return 0.5f * v * (1.0f + erfv);
}

// ---------------------------------------------------------------------------
// K1: q = xh@W1^T + b1, k = xh@W2^T + b2 as tiled GEMM (fp32 FMA).
// Epilogue writes hi/lo bf16 pairs directly.
// ---------------------------------------------------------------------------
__global__ __launch_bounds__(256) void k_qk(const float* __restrict__ x,
        const float* __restrict__ W1, const float* __restrict__ b1,
        const float* __restrict__ W2, const float* __restrict__ b2,
        ushort* __restrict__ qh, ushort* __restrict__ ql,
        ushort* __restrict__ kh, ushort* __restrict__ kl) {
    int blk = blockIdx.x;              // b*64 + h*8 + lt
    int b = blk >> 6, h = (blk >> 3) & 7, lt = blk & 7;
    __shared__ float xt[64][68];       // [l][c]
    __shared__ float w1t[64][68];      // [d][c]
    __shared__ float w2t[64][68];
    int tid = threadIdx.x;
    #pragma unroll
    for (int r = 0; r < 16; ++r) {
        int e = tid + r * 256;
        int rr = e >> 6, cc = e & 63;
        xt[rr][cc]  = x[(b * kL + lt * 64 + rr) * kD + h * kDH + cc];
        w1t[rr][cc] = W1[rr * 64 + cc];
        w2t[rr][cc] = W2[rr * 64 + cc];
    }
    __syncthreads();
    int ty = tid >> 4, tx = tid & 15;
    float aq[4][4] = {}, ak[4][4] = {};
    #pragma unroll 2
    for (int c = 0; c < 64; c += 4) {
        float4 av[4], wq[4], wk[4];
        #pragma unroll
        for (int a = 0; a < 4; ++a) av[a] = *(const float4*)&xt[ty * 4 + a][c];
        #pragma unroll
        for (int j = 0; j < 4; ++j) {
            wq[j] = *(const float4*)&w1t[tx + 16 * j][c];
            wk[j] = *(const float4*)&w2t[tx + 16 * j][c];
        }
        #pragma unroll
        for (int a = 0; a < 4; ++a)
            #pragma unroll
            for (int j = 0; j < 4; ++j) {
                aq[a][j] = fmaf(av[a].x, wq[j].x, aq[a][j]);
                aq[a][j] = fmaf(av[a].y, wq[j].y, aq[a][j]);
                aq[a][j] = fmaf(av[a].z, wq[j].z, aq[a][j]);
                aq[a][j] = fmaf(av[a].w, wq[j].w, aq[a][j]);
                ak[a][j] = fmaf(av[a].x, wk[j].x, ak[a][j]);
                ak[a][j] = fmaf(av[a].y, wk[j].y, ak[a][j]);
                ak[a][j] = fmaf(av[a].z, wk[j].z, ak[a][j]);
                ak[a][j] = fmaf(av[a].w, wk[j].w, ak[a][j]);
            }
    }
    #pragma unroll
    for (int a = 0; a < 4; ++a)
        #pragma unroll
        for (int j = 0; j < 4; ++j) {
            int row = lt * 64 + ty * 4 + a;
            int col = tx + 16 * j;
            int o = ((b * kH + h) * kL + row) * kDH + col;
            float qv = aq[a][j] + b1[col];
            float kv = ak[a][j] + b2[col];
            ushort qhh = f2bf(qv), khh = f2bf(kv);
            qh[o] = qhh; ql[o] = f2bf(qv - bf2f(qhh));
            kh[o] = khh; kl[o] = f2bf(kv - bf2f(khh));
        }
}

// ---------------------------------------------------------------------------
// K2 (MFMA, split-bf16): adj = gelu(q @ k^T) per (b,h). 64x64 tile, K=64.
// ---------------------------------------------------------------------------
__global__ __launch_bounds__(256) void k_adj(const ushort* __restrict__ qh,
        const ushort* __restrict__ ql, const ushort* __restrict__ kh,
        const ushort* __restrict__ kl, float* __restrict__ adj) {
    int blk = blockIdx.x;
    int bh = blk >> 6;
    int it = (blk >> 3) & 7, jt = blk & 7;
    __shared__ ushort ah[64][72], al[64][72];
    __shared__ ushort bh_[64][72], bl[64][72];
    int tid = threadIdx.x;
    int r = tid >> 2, s = tid & 3;
    size_t aoff = (size_t)(bh * kL + it * 64 + r) * kDH + s * 16;
    size_t boff = (size_t)(bh * kL + jt * 64 + r) * kDH + s * 16;
    *(int4*)&ah[r][s * 16]  = *(const int4*)&qh[aoff];
    *(int4*)&ah[r][s * 16 + 8]  = *(const int4*)&qh[aoff + 8];
    *(int4*)&al[r][s * 16]  = *(const int4*)&ql[aoff];
    *(int4*)&al[r][s * 16 + 8]  = *(const int4*)&ql[aoff + 8];
    *(int4*)&bh_[r][s * 16] = *(const int4*)&kh[boff];
    *(int4*)&bh_[r][s * 16 + 8] = *(const int4*)&kh[boff + 8];
    *(int4*)&bl[r][s * 16]  = *(const int4*)&kl[boff];
    *(int4*)&bl[r][s * 16 + 8]  = *(const int4*)&kl[boff + 8];
    __syncthreads();
    int lane = tid & 63, wave = tid >> 6;
    int wm = wave >> 1, wn = wave & 1;
    int am = wm * 32 + (lane & 15);
    int bn = wn * 32 + (lane & 15);
    int coff = (lane >> 4) * 8;
    f32x4 acc[2][2] = {};
    #pragma unroll
    for (int kk = 0; kk < 2; ++kk) {
        bf16x8 afh[2], afl[2], bfh[2], bfl[2];
        #pragma unroll
        for (int fm = 0; fm < 2; ++fm) {
            afh[fm] = *(const bf16x8*)&ah[am + fm * 16][kk * 32 + coff];
            afl[fm] = *(const bf16x8*)&al[am + fm * 16][kk * 32 + coff];
        }
        #pragma unroll
        for (int fn = 0; fn < 2; ++fn) {
            bfh[fn] = *(const bf16x8*)&bh_[bn + fn * 16][kk * 32 + coff];
            bfl[fn] = *(const bf16x8*)&bl[bn + fn * 16][kk * 32 + coff];
        }
        #pragma unroll
        for (int fm = 0; fm < 2; ++fm)
            #pragma unroll
            for (int fn = 0; fn < 2; ++fn) {
                acc[fm][fn] = __builtin_amdgcn_mfma_f32_16x16x32_bf16(
                    afh[fm], bfh[fn], acc[fm][fn], 0, 0, 0);
                acc[fm][fn] = __builtin_amdgcn_mfma_f32_16x16x32_bf16(
                    afh[fm], bfl[fn], acc[fm][fn], 0, 0, 0);
                acc[fm][fn] = __builtin_amdgcn_mfma_f32_16x16x32_bf16(
                    afl[fm], bfh[fn], acc[fm][fn], 0, 0, 0);
            }
    }
    int mrow = it * 64 + wm * 32 + (lane >> 4) * 4;
    int ncol = jt * 64 + wn * 32 + (lane & 15);
    #pragma unroll
    for (int fm = 0; fm < 2; ++fm)
        #pragma unroll
        for (int fn = 0; fn < 2; ++fn)
            #pragma unroll
            for (int rr = 0; rr < 4; ++rr)
                adj[((size_t)bh * kL + mrow + fm * 16 + rr) * kL + ncol + fn * 16] =
                    gelu_fast(acc[fm][fn][rr]);
}

// ---------------------------------------------------------------------------
// K3 (fused): TWO rows per wave, interleaved (independent serial chains
// overlap -> ~2x on the latency-bound bisection/reduction phases).
// Exact 256th-smallest via integer-key ballot bisection (full 32-bit walk,
// boundary early-exits, integer extraction). Then threshold, logits
// (Wg fragments shared by both rows), softmax-3, top-p, computed masks,
// row softmax, bf16 adjb write. grid = ROWS/8 blocks of 256.
// ---------------------------------------------------------------------------
__global__ __launch_bounds__(256) void k_select(const float* __restrict__ adj,
        const float* __restrict__ Wg,
        ushort* __restrict__ adjb,
        float* __restrict__ spbuf, float* __restrict__ entbuf) {
    int tid = threadIdx.x;
    int wave = tid >> 6, lane = tid & 63;
    int row0 = blockIdx.x * 8 + wave * 2;
    int j0 = lane * 8;

    float v[2][8];
    unsigned key[2][8];
    #pragma unroll
    for (int r = 0; r < 2; ++r) {
        const float* arow = adj + (size_t)(row0 + r) * kL;
        float4 a0 = *(const float4*)&arow[j0];
        float4 a1 = *(const float4*)&arow[j0 + 4];
        v[r][0] = a0.x; v[r][1] = a0.y; v[r][2] = a0.z; v[r][3] = a0.w;
        v[r][4] = a1.x; v[r][5] = a1.y; v[r][6] = a1.z; v[r][7] = a1.w;
        #pragma unroll
        for (int t = 0; t < 8; ++t) key[r][t] = mapf(v[r][t]);
    }

    // interleaved bisection, k = 255 (0-indexed), integer key space
    unsigned prefix[2] = {0u, 0u};
    int cbp[2] = {0, 0}, cin[2] = {512, 512}, bitv[2] = {31, 31};
    int mode[2] = {0, 0};               // 0: exhausted, 1: extract-min, 2: extract-max
    bool act0 = true, act1 = true;
    while (act0 || act1) {
        if (act0) {
            unsigned cand = prefix[0] | (1u << bitv[0]);
            int c = 0;
            #pragma unroll
            for (int t = 0; t < 8; ++t)
                c += (int)__popcll(__ballot(key[0][t] < cand));
            if (255 < c) cin[0] = c - cbp[0];
            else { cin[0] -= (c - cbp[0]); prefix[0] = cand; cbp[0] = c; }
            --bitv[0];
            int loc = 255 - cbp[0];
            if (cin[0] == 1)           { mode[0] = 2; act0 = false; }
            else if (loc == 0)         { mode[0] = 1; act0 = false; }
            else if (loc == cin[0] - 1){ mode[0] = 2; act0 = false; }
            else if (bitv[0] < 0)      { mode[0] = 0; act0 = false; }
        }
        if (act1) {
            unsigned cand = prefix[1] | (1u << bitv[1]);
            int c = 0;
            #pragma unroll
            for (int t = 0; t < 8; ++t)
                c += (int)__popcll(__ballot(key[1][t] < cand));
            if (255 < c) cin[1] = c - cbp[1];
            else { cin[1] -= (c - cbp[1]); prefix[1] = cand; cbp[1] = c; }
            --bitv[1];
            int loc = 255 - cbp[1];
            if (cin[1] == 1)           { mode[1] = 2; act1 = false; }
            else if (loc == 0)         { mode[1] = 1; act1 = false; }
            else if (loc == cin[1] - 1){ mode[1] = 2; act1 = false; }
            else if (bitv[1] < 0)      { mode[1] = 0; act1 = false; }
        }
    }
    float thr[2];
    #pragma unroll
    for (int r = 0; r < 2; ++r) {
        if (mode[r] == 0) {
            thr[r] = unmapf(prefix[r]); // all bits resolved: exact key
        } else {
            unsigned width = 1u << (bitv[r] + 1);   // bitv in [-1,30]
            unsigned acc = (mode[r] == 1) ? 0xFFFFFFFFu : 0u;
            #pragma unroll
            for (int t = 0; t < 8; ++t) {
                unsigned d = key[r][t] - prefix[r];
                bool mem = d < width;
                if (mode[r] == 1) acc = (mem && key[r][t] < acc) ? key[r][t] : acc;
                else              acc = (mem && key[r][t] > acc) ? key[r][t] : acc;
            }
            if (mode[r] == 1) {
                #pragma unroll
                for (int off = 1; off < 64; off <<= 1)
                    acc = min(acc, (unsigned)__shfl_xor((int)acc, off));
            } else {
                #pragma unroll
                for (int off = 1; off < 64; off <<= 1)
                    acc = max(acc, (unsigned)__shfl_xor((int)acc, off));
            }
            thr[r] = unmapf(acc);
        }
    }

    // Wg fragments (shared by both rows -- same j0)
    union { float4 f4[2]; float f[8]; } wg0, wg1, wg2;
    wg0.f4[0] = *(const float4*)&Wg[j0];          wg0.f4[1] = *(const float4*)&Wg[j0 + 4];
    wg1.f4[0] = *(const float4*)&Wg[kL + j0];     wg1.f4[1] = *(const float4*)&Wg[kL + j0 + 4];
    wg2.f4[0] = *(const float4*)&Wg[2 * kL + j0]; wg2.f4[1] = *(const float4*)&Wg[2 * kL + j0 + 4];

    // threshold + logits (both rows, chains interleave)
    float l[2][3] = {};
    #pragma unroll
    for (int r = 0; r < 2; ++r)
        #pragma unroll
        for (int t = 0; t < 8; ++t) {
            float nv = (v[r][t] > thr[r]) ? v[r][t] : 0.0f;
            v[r][t] = nv;
            l[r][0] = fmaf(nv, wg0.f[t], l[r][0]);
            l[r][1] = fmaf(nv, wg1.f[t], l[r][1]);
            l[r][2] = fmaf(nv, wg2.f[t], l[r][2]);
        }
    #pragma unroll
    for (int off = 1; off < 64; off <<= 1) {
        #pragma unroll
        for (int r = 0; r < 2; ++r) {
            l[r][0] += __shfl_xor(l[r][0], off);
            l[r][1] += __shfl_xor(l[r][1], off);
            l[r][2] += __shfl_xor(l[r][2], off);
        }
    }

    float g[2][3];
    #pragma unroll
    for (int r = 0; r < 2; ++r) {
        int row = row0 + r;
        float m = fmaxf(l[r][0], fmaxf(l[r][1], l[r][2]));
        float e0 = __expf(l[r][0] - m), e1 = __expf(l[r][1] - m), e2 = __expf(l[r][2] - m);
        float s = e0 + e1 + e2;
        float p[3] = {e0 / s, e1 / s, e2 / s};
        int o0, o1, o2;
        if (p[0] >= p[1] && p[0] >= p[2]) o0 = 0;
        else if (p[1] >= p[2]) o0 = 1;
        else o0 = 2;
        int r0 = (o0 == 0) ? 1 : 0;
        int r1 = (o0 == 2) ? 1 : 2;
        if (p[r0] >= p[r1]) { o1 = r0; o2 = r1; } else { o1 = r1; o2 = r0; }
        float sp0 = p[o0], sp1 = p[o1], sp2 = p[o2];
        float c0 = sp0, c1 = sp0 + sp1, c2 = c1 + sp2;
        bool m0 = c0 > 0.5f, m1 = c1 > 0.5f, m2 = c2 > 0.5f;
        int ti = m0 ? 0 : (m1 ? 1 : 2);
        bool mm0 = m0 && (ti != 0);
        bool mm1 = m1 && (ti != 1);
        bool mm2 = m2 && (ti != 2);
        g[r][0] = 0.f; g[r][1] = 0.f; g[r][2] = 0.f;
        g[r][o0] = mm0 ? 0.f : 1.f;
        g[r][o1] = mm1 ? 0.f : 1.f;
        g[r][o2] = mm2 ? 0.f : 1.f;
        if (lane == 0) {
            spbuf[row * 3 + 0] = mm0 ? 0.f : sp0;
            spbuf[row * 3 + 1] = mm1 ? 0.f : sp1;
            spbuf[row * 3 + 2] = mm2 ? 0.f : sp2;
            entbuf[row] = p[0] * __logf(p[0] + 1e-10f) +
                          p[1] * __logf(p[1] + 1e-10f) +
                          p[2] * __logf(p[2] + 1e-10f);
        }
    }

    // computed masks + masked row softmax + bf16 store (both rows)
    int lane8 = (lane & 7) * 8;
    float av[2][8];
    #pragma unroll
    for (int r = 0; r < 2; ++r) {
        int i = (row0 + r) & (kL - 1);
        int i6 = i >> 6, i63 = i & 63;
        bool inb = ((lane >> 3) == i6);
        float sel1 = inb ? (g[r][1] + 1.0f) : g[r][0];
        float sel0 = inb ? g[r][1] : g[r][2];
        #pragma unroll
        for (int t = 0; t < 8; ++t) {
            bool ing = (lane8 + t) == i63;
            av[r][t] = v[r][t] * (ing ? sel1 : sel0);
        }
    }
    float mx[2];
    #pragma unroll
    for (int r = 0; r < 2; ++r) {
        float m2_ = fmaxf(fmaxf(fmaxf(av[r][0], av[r][1]), fmaxf(av[r][2], av[r][3])),
                          fmaxf(fmaxf(av[r][4], av[r][5]), fmaxf(av[r][6], av[r][7])));
        mx[r] = m2_;
    }
    #pragma unroll
    for (int off = 1; off < 64; off <<= 1) {
        mx[0] = fmaxf(mx[0], __shfl_xor(mx[0], off));
        mx[1] = fmaxf(mx[1], __shfl_xor(mx[1], off));
    }
    float e[2][8], ls[2] = {0.f, 0.f};
    #pragma unroll
    for (int r = 0; r < 2; ++r)
        #pragma unroll
        for (int t = 0; t < 8; ++t) { e[r][t] = __expf(av[r][t] - mx[r]); ls[r] += e[r][t]; }
    #pragma unroll
    for (int off = 1; off < 64; off <<= 1) {
        ls[0] += __shfl_xor(ls[0], off);
        ls[1] += __shfl_xor(ls[1], off);
    }
    #pragma unroll
    for (int r = 0; r < 2; ++r) {
        float inv = 1.0f / ls[r];
        union { ushort u[8]; int4 vv; } pk;
        #pragma unroll
        for (int t = 0; t < 8; ++t) pk.u[t] = f2bf(e[r][t] * inv);
        *(int4*)&adjb[(size_t)(row0 + r) * kL + j0] = pk.vv;
    }
}

// ---------------------------------------------------------------------------
// K4 (MFMA, bf16): xp = x @ Wp^T + bp, written TRANSPOSED bf16:
// xpbT[dcol][b*L + l].
// ---------------------------------------------------------------------------
__global__ __launch_bounds__(256) void k_xp(const float* __restrict__ x,
        const float* __restrict__ Wp, const float* __restrict__ bp,
        ushort* __restrict__ xpbT) {
    int it = blockIdx.x >> 3, jt = blockIdx.x & 7;   // it: l-rows, jt: d-cols
    __shared__ ushort xbs[64][72];
    __shared__ ushort wbs[64][72];
    int tid = threadIdx.x;
    int r = tid >> 2, s = tid & 3;
    int lane = tid & 63, wave = tid >> 6;
    int wm = wave >> 1, wn = wave & 1;
    int am = wm * 32 + (lane & 15);
    int bn = wn * 32 + (lane & 15);
    int coff = (lane >> 4) * 8;
    f32x4 acc[2][2] = {};
    const float* xsrc = x + (size_t)(it * 64 + r) * kD + s * 16;
    const float* wsrc = Wp + (size_t)(jt * 64 + r) * kD + s * 16;
    for (int kt = 0; kt < 8; ++kt) {
        union { ushort u[16]; int4 v[2]; } px, pw;
        #pragma unroll
        for (int c4 = 0; c4 < 4; ++c4) {
            float4 fx = *(const float4*)(xsrc + kt * 64 + c4 * 4);
            float4 fw = *(const float4*)(wsrc + kt * 64 + c4 * 4);
            px.u[c4 * 4 + 0] = f2bf(fx.x); px.u[c4 * 4 + 1] = f2bf(fx.y);
            px.u[c4 * 4 + 2] = f2bf(fx.z); px.u[c4 * 4 + 3] = f2bf(fx.w);
            pw.u[c4 * 4 + 0] = f2bf(fw.x); pw.u[c4 * 4 + 1] = f2bf(fw.y);
            pw.u[c4 * 4 + 2] = f2bf(fw.z); pw.u[c4 * 4 + 3] = f2bf(fw.w);
        }
        __syncthreads();
        *(int4*)&xbs[r][s * 16] = px.v[0];
        *(int4*)&xbs[r][s * 16 + 8] = px.v[1];
        *(int4*)&wbs[r][s * 16] = pw.v[0];
        *(int4*)&wbs[r][s * 16 + 8] = pw.v[1];
        __syncthreads();
        #pragma unroll
        for (int kk = 0; kk < 2; ++kk) {
            bf16x8 af[2], bf[2];
            #pragma unroll
            for (int fm = 0; fm < 2; ++fm)
                af[fm] = *(const bf16x8*)&xbs[am + fm * 16][kk * 32 + coff];
            #pragma unroll
            for (int fn = 0; fn < 2; ++fn)
                bf[fn] = *(const bf16x8*)&wbs[bn + fn * 16][kk * 32 + coff];
            #pragma unroll
            for (int fm = 0; fm < 2; ++fm)
                #pragma unroll
                for (int fn = 0; fn < 2; ++fn)
                    acc[fm][fn] = __builtin_amdgcn_mfma_f32_16x16x32_bf16(
                        af[fm], bf[fn], acc[fm][fn], 0, 0, 0);
        }
    }
    // epilogue: add bias, store transposed (4 consecutive l per lane)
    #pragma unroll
    for (int fn = 0; fn < 2; ++fn) {
        int dcol = jt * 64 + wn * 32 + (lane & 15) + fn * 16;
        float bpv = bp[dcol];
        #pragma unroll
        for (int fm = 0; fm < 2; ++fm) {
            int l0 = it * 64 + wm * 32 + fm * 16 + (lane >> 4) * 4;
            union { ushort u[4]; uint2 v; } pk;
            #pragma unroll
            for (int rr = 0; rr < 4; ++rr)
                pk.u[rr] = f2bf(acc[fm][fn][rr] + bpv);
            *(uint2*)&xpbT[(size_t)dcol * (size_t)(kB * kL) + l0] = pk.v;
        }
    }
}

// ---------------------------------------------------------------------------
// K6 (MFMA): out[b, i, h*64+d] = sum_j adjb[bh,i,j] * xpbT[h*64+d][b*512+j]
// ---------------------------------------------------------------------------
__global__ __launch_bounds__(256) void k_out(const ushort* __restrict__ adjb,
        const ushort* __restrict__ xpbT, float* __restrict__ out) {
    int blk = blockIdx.x;
    int bh = blk >> 3, it = blk & 7;
    int b = bh >> 3, h = bh & 7;
    __shared__ ushort as_[64][72];
    __shared__ ushort bs_[64][72];
    int tid = threadIdx.x;
    int lane = tid & 63, wave = tid >> 6;
    int wm = wave >> 1, wn = wave & 1;
    int r = tid >> 2, s = tid & 3;
    const ushort* aG = adjb + ((size_t)(bh * kL + it * 64 + r)) * kL + s * 16;
    const ushort* bG = xpbT + ((size_t)(h * kDH + r)) * (size_t)(kB * kL) + b * kL + s * 16;
    f32x4 acc[2][2] = {};
    int am = wm * 32 + (lane & 15);
    int bn = wn * 32 + (lane & 15);
    int coff = (lane >> 4) * 8;
    for (int kt = 0; kt < 8; ++kt) {
        int4 a0 = *(const int4*)(aG + kt * 64);
        int4 a1 = *(const int4*)(aG + kt * 64 + 8);
        int4 b0 = *(const int4*)(bG + kt * 64);
        int4 b1 = *(const int4*)(bG + kt * 64 + 8);
        __syncthreads();
        *(int4*)&as_[r][s * 16] = a0;
        *(int4*)&as_[r][s * 16 + 8] = a1;
        *(int4*)&bs_[r][s * 16] = b0;
        *(int4*)&bs_[r][s * 16 + 8] = b1;
        __syncthreads();
        #pragma unroll
        for (int kk = 0; kk < 2; ++kk) {
            bf16x8 af[2], bf[2];
            #pragma unroll
            for (int fm = 0; fm < 2; ++fm)
                af[fm] = *(const bf16x8*)&as_[am + fm * 16][kk * 32 + coff];
            #pragma unroll
            for (int fn = 0; fn < 2; ++fn)
                bf[fn] = *(const bf16x8*)&bs_[bn + fn * 16][kk * 32 + coff];
            #pragma unroll
            for (int fm = 0; fm < 2; ++fm)
                #pragma unroll
                for (int fn = 0; fn < 2; ++fn)
                    acc[fm][fn] = __builtin_amdgcn_mfma_f32_16x16x32_bf16(
                        af[fm], bf[fn], acc[fm][fn], 0, 0, 0);
        }
    }
    int mrow = it * 64 + wm * 32 + (lane >> 4) * 4;
    int ncol = h * kDH + wn * 32 + (lane & 15);
    #pragma unroll
    for (int fm = 0; fm < 2; ++fm)
        #pragma unroll
        for (int fn = 0; fn < 2; ++fn)
            #pragma unroll
            for (int rr = 0; rr < 4; ++rr)
                out[((size_t)b * kL + mrow + fm * 16 + rr) * kD + ncol + fn * 16] =
                    acc[fm][fn][rr];
}

// ---------------------------------------------------------------------------
// K7: finalize loss (single block, deterministic reductions)
// ---------------------------------------------------------------------------
__global__ __launch_bounds__(1024) void k_loss(const float* __restrict__ spbuf,
        const float* __restrict__ entbuf, float* __restrict__ out_loss) {
    __shared__ float imps[kL * 3];
    __shared__ float red[1024];
    int tid = threadIdx.x;
    for (int idx = tid; idx < kL * 3; idx += 1024) {
        float s = 0.f;
        for (int bh = 0; bh < kBH; ++bh)
            s += spbuf[bh * kL * 3 + idx];
        imps[idx] = s;
    }
    float es = 0.f;
    for (int idx = tid; idx < kROWS; idx += 1024) es += entbuf[idx];
    red[tid] = es;
    __syncthreads();
    for (int s = 512; s > 0; s >>= 1) {
        if (tid < s) red[tid] += red[tid + s];
        __syncthreads();
    }
    float ent_total = red[0];
    __syncthreads();
    float ms = 0.f;
    for (int idx = tid; idx < kL * 3; idx += 1024) ms += imps[idx];
    red[tid] = ms;
    __syncthreads();
    for (int s = 512; s > 0; s >>= 1) {
        if (tid < s) red[tid] += red[tid + s];
        __syncthreads();
    }
    float mean = red[0] / (float)(kL * 3);
    __syncthreads();
    float vs = 0.f;
    for (int idx = tid; idx < kL * 3; idx += 1024) {
        float d = imps[idx] - mean;
        vs += d * d;
    }
    red[tid] = vs;
    __syncthreads();
    for (int s = 512; s > 0; s >>= 1) {
        if (tid < s) red[tid] += red[tid + s];
        __syncthreads();
    }
    if (tid == 0) {
        float var = red[0] / (float)(kL * 3 - 1);
        float loss_imp = var / (mean * mean + 1e-10f);
        float loss_dyn = -ent_total / (float)(kBH * 3);
        out_loss[0] = loss_imp + 0.1f * loss_dyn;
    }
}

// ---------------------------------------------------------------------------
extern "C" void kernel_launch(void* const* d_in, const int* in_sizes, int n_in,
                              void* d_out, int out_size, void* d_ws, size_t ws_size,
                              hipStream_t stream) {
    const float* x     = (const float*)d_in[0];
    const float* W1    = (const float*)d_in[2];
    const float* b1    = (const float*)d_in[3];
    const float* W2    = (const float*)d_in[4];
    const float* b2    = (const float*)d_in[5];
    const float* Wg    = (const float*)d_in[6];
    const float* Wp    = (const float*)d_in[7];
    const float* bp    = (const float*)d_in[8];
    float* out = (float*)d_out;
    float* ws  = (float*)d_ws;

    // workspace layout (float units). adjb overlays qh/ql/kh/kl (dead after
    // k_adj; stream order serializes k_adj -> k_select).
    float*  adj   = ws;                          // [0, 16777216)
    ushort* qh    = (ushort*)(ws + 16777216);
    ushort* ql    = (ushort*)(ws + 17825792);
    ushort* kh    = (ushort*)(ws + 18874368);
    ushort* kl    = (ushort*)(ws + 19922944);
    ushort* adjb  = (ushort*)(ws + 16777216);    // overlays qh..kl + extra
    ushort* xpbT  = (ushort*)(ws + 25165824);
    float*  spbuf = ws + 26214400;               // 98,304
    float*  entbuf= ws + 26312704;               // 32,768

    k_qk<<<512, 256, 0, stream>>>(x, W1, b1, W2, b2, qh, ql, kh, kl);
    k_adj<<<kBH * 64, 256, 0, stream>>>(qh, ql, kh, kl, adj);
    k_select<<<kROWS / 8, 256, 0, stream>>>(adj, Wg, adjb, spbuf, entbuf);
    k_xp<<<512, 256, 0, stream>>>(x, Wp, bp, xpbT);
    k_out<<<512, 256, 0, stream>>>(adjb, xpbT, out);
    k_loss<<<1, 1024, 0, stream>>>(spbuf, entbuf, out + (size_t)kB * kL * kD);
}